// Round 2
// baseline (1349.888 us; speedup 1.0000x reference)
//
#include <hip/hip_runtime.h>
#include <cstdint>
#include <cstddef>

#define NN 512   // nodes per graph
#define NE 8192  // edges
#define FF 64    // in features
#define HH 128   // out features
#define BT 768   // B*T graphs

// ---------------------------------------------------------------------------
// Setup: degree -> dinv, CSR by dst. One block, 512 threads. Runs every call
// (ws is re-poisoned). Cost is negligible (~few us).
// edge_index arrives as INT32 (JAX x64 disabled; harness: integer -> int*).
// ---------------------------------------------------------------------------
__global__ __launch_bounds__(512) void gcn_setup(
    const int* __restrict__ ei,        // [2, NE] int32: row0=src, row1=dst
    float* __restrict__ dinv,          // [NN]
    int* __restrict__ csr_ptr,         // [NN+1]
    int* __restrict__ csr_src)         // [NE]
{
    __shared__ int cnt[NN];
    __shared__ int scan[NN];
    __shared__ int offs[NN];
    const int tid = threadIdx.x;  // 0..511, NN==512

    cnt[tid] = 0;
    __syncthreads();
    for (int e = tid; e < NE; e += 512) {
        atomicAdd(&cnt[ei[NE + e]], 1);
    }
    __syncthreads();

    const int v = cnt[tid];
    scan[tid] = v;
    __syncthreads();
    // Hillis-Steele inclusive scan
    for (int off = 1; off < NN; off <<= 1) {
        const int t = (tid >= off) ? scan[tid - off] : 0;
        __syncthreads();
        scan[tid] += t;
        __syncthreads();
    }
    const int excl = scan[tid] - v;
    offs[tid] = excl;
    csr_ptr[tid] = excl;
    if (tid == NN - 1) csr_ptr[NN] = scan[tid];  // == NE
    // self-loop included: deg = cnt + 1 (always > 0)
    dinv[tid] = rsqrtf((float)(v + 1));
    __syncthreads();

    for (int e = tid; e < NE; e += 512) {
        const int d = ei[NE + e];
        const int s = ei[e];
        const int p = atomicAdd(&offs[d], 1);
        csr_src[p] = s;
    }
}

// ---------------------------------------------------------------------------
// Fused main kernel: per (graph bt, 64-node tile):
//   Phase 1: Y[n, f] = dinv[n] * ( dinv[n]*x[n,f] + sum_{s in N(n)} dinv[s]*x[s,f] )
//            -> LDS (64 x 64, padded to 65)
//   Phase 2: out[n, h] = sum_f Y[n,f] * W[f,h] + b[h]   (f32 register GEMM)
// ---------------------------------------------------------------------------
__global__ __launch_bounds__(256) void gcn_main(
    const float* __restrict__ x,      // [BT, NN, FF]
    const float* __restrict__ W,      // [FF, HH]
    const float* __restrict__ bias,   // [HH]
    const float* __restrict__ dinv,   // [NN]
    const int* __restrict__ csr_ptr,  // [NN+1]
    const int* __restrict__ csr_src,  // [NE]
    float* __restrict__ out)          // [BT, NN, HH]
{
    __shared__ float Wl[FF * HH];     // 32 KB
    __shared__ float Yl[64 * 65];     // 16.25 KB, +1 pad kills column bank conflict

    const int tid  = threadIdx.x;
    const int bt   = blockIdx.y;
    const int tile = blockIdx.x;      // 0..7

    // Stage W (coalesced float4)
    for (int i = tid; i < FF * HH / 4; i += 256) {
        ((float4*)Wl)[i] = ((const float4*)W)[i];
    }

    // ---- Phase 1: aggregation. One wave per node (wave-uniform neighbor loop),
    // lane = feature index -> 256B coalesced x-row reads.
    const int wave = tid >> 6;
    const int lane = tid & 63;
    const float* xg = x + (size_t)bt * (NN * FF);

    for (int it = 0; it < 16; ++it) {
        const int nl = it * 4 + wave;       // 0..63 within tile
        const int n  = tile * 64 + nl;      // global node id
        const float di = dinv[n];
        const int p0 = csr_ptr[n];
        const int p1 = csr_ptr[n + 1];
        float acc = di * xg[n * FF + lane];  // self-loop (x dinv[n] again below)
        for (int p = p0; p < p1; ++p) {
            const int s = csr_src[p];
            acc = fmaf(dinv[s], xg[s * FF + lane], acc);
        }
        Yl[nl * 65 + lane] = di * acc;
    }
    __syncthreads();

    // ---- Phase 2: (64 x 64) @ (64 x 128) f32 GEMM, 4x8 micro-tile per thread
    const int rg = tid >> 4;   // 0..15 -> rows rg*4 .. rg*4+3
    const int cg = tid & 15;   // 0..15 -> cols cg*8 .. cg*8+7
    float acc[4][8];
#pragma unroll
    for (int r = 0; r < 4; ++r)
#pragma unroll
        for (int c = 0; c < 8; ++c) acc[r][c] = 0.f;

    for (int k = 0; k < 64; ++k) {
        float a[4];
#pragma unroll
        for (int r = 0; r < 4; ++r) a[r] = Yl[(rg * 4 + r) * 65 + k];
        const float4 b0 = *(const float4*)&Wl[k * HH + cg * 8];
        const float4 b1 = *(const float4*)&Wl[k * HH + cg * 8 + 4];
        const float bv[8] = {b0.x, b0.y, b0.z, b0.w, b1.x, b1.y, b1.z, b1.w};
#pragma unroll
        for (int r = 0; r < 4; ++r)
#pragma unroll
            for (int c = 0; c < 8; ++c)
                acc[r][c] = fmaf(a[r], bv[c], acc[r][c]);
    }

    // ---- Epilogue: + bias, float4 stores
    float* og = out + ((size_t)bt * NN + (size_t)tile * 64) * HH;
#pragma unroll
    for (int r = 0; r < 4; ++r) {
        float4 o0, o1;
        o0.x = acc[r][0] + bias[cg * 8 + 0];
        o0.y = acc[r][1] + bias[cg * 8 + 1];
        o0.z = acc[r][2] + bias[cg * 8 + 2];
        o0.w = acc[r][3] + bias[cg * 8 + 3];
        o1.x = acc[r][4] + bias[cg * 8 + 4];
        o1.y = acc[r][5] + bias[cg * 8 + 5];
        o1.z = acc[r][6] + bias[cg * 8 + 6];
        o1.w = acc[r][7] + bias[cg * 8 + 7];
        const int row = rg * 4 + r;
        *(float4*)&og[row * HH + cg * 8]     = o0;
        *(float4*)&og[row * HH + cg * 8 + 4] = o1;
    }
}

extern "C" void kernel_launch(void* const* d_in, const int* in_sizes, int n_in,
                              void* d_out, int out_size, void* d_ws, size_t ws_size,
                              hipStream_t stream) {
    const float* x  = (const float*)d_in[0];
    const int*   ei = (const int*)d_in[1];     // int32 (JAX x64 disabled)
    const float* W  = (const float*)d_in[2];
    const float* b  = (const float*)d_in[3];
    float* out = (float*)d_out;

    // Workspace layout (all 4B-aligned): dinv[512] | csr_ptr[513] | csr_src[8192]
    float* dinv    = (float*)d_ws;
    int*   csr_ptr = (int*)d_ws + NN;
    int*   csr_src = csr_ptr + (NN + 1);

    hipLaunchKernelGGL(gcn_setup, dim3(1), dim3(512), 0, stream,
                       ei, dinv, csr_ptr, csr_src);
    hipLaunchKernelGGL(gcn_main, dim3(8, BT), dim3(256), 0, stream,
                       x, W, b, dinv, csr_ptr, csr_src, out);
}